// Round 1
// 300.662 us; speedup vs baseline: 1.0052x; 1.0052x over previous
//
#include <hip/hip_runtime.h>
#include <cstdint>
#include <cstddef>

// Problem constants (B=8192, P=8192, F=256; SIGMA=1 -> denom = 2)
#define B_ROWS 8192
#define P_ROWS 8192
#define FDIM   256

// GEMM tiling (m97-ladder structure: 128x128 tile, 4 waves, 4x4 16x16x32 MFMA)
#define BM 128
#define BN 128
#define BK 64
#define NSTEP (FDIM / BK)   // 4 K-steps

typedef __bf16  bf16x8  __attribute__((ext_vector_type(8)));
typedef float   floatx4 __attribute__((ext_vector_type(4)));

// round-to-nearest-even fp32 -> bf16 (inputs are finite Gaussians, no NaN path)
__device__ __forceinline__ unsigned short f2bf(float f) {
  unsigned int u = __float_as_uint(f);
  u += 0x7fffu + ((u >> 16) & 1u);
  return (unsigned short)(u >> 16);
}

// async global->LDS, 16B per lane. LDS dest is wave-uniform base + lane*16.
__device__ __forceinline__ void async16(const void* g, void* l) {
  __builtin_amdgcn_global_load_lds(
      (const __attribute__((address_space(1))) void*)g,
      (__attribute__((address_space(3))) void*)l,
      16, 0, 0);
}

// ---------------------------------------------------------------------------
// Pre-pass: convert x / prototypes to bf16 planes in ws, compute fp32 row
// norms. One wave per row (64 lanes x float4 = 256 elems).
// ---------------------------------------------------------------------------
__global__ void __launch_bounds__(64) prep_kernel(
    const float* __restrict__ x, const float* __restrict__ p,
    unsigned short* __restrict__ xbf, unsigned short* __restrict__ pbf,
    float* __restrict__ x2, float* __restrict__ p2) {
  const int row  = blockIdx.x;
  const int lane = threadIdx.x;

  const float* src;
  unsigned short* dst;
  float* nrm;
  int r;
  if (row < B_ROWS) { src = x; dst = xbf; nrm = x2; r = row; }
  else              { src = p; dst = pbf; nrm = p2; r = row - B_ROWS; }

  const float4 v = *reinterpret_cast<const float4*>(src + (size_t)r * FDIM + lane * 4);
  float s = v.x * v.x + v.y * v.y + v.z * v.z + v.w * v.w;
  #pragma unroll
  for (int o = 32; o > 0; o >>= 1) s += __shfl_down(s, o);
  if (lane == 0) nrm[r] = s;

  ushort4 pk;
  pk.x = f2bf(v.x); pk.y = f2bf(v.y); pk.z = f2bf(v.z); pk.w = f2bf(v.w);
  *reinterpret_cast<ushort4*>(dst + (size_t)r * FDIM + lane * 4) = pk;
}

// ---------------------------------------------------------------------------
// Main kernel: C = X * P^T (both K-contiguous) with distance+exp epilogue.
//
// LDS layout: [row][8 chunks of 16B] per BK=64 K-slice; chunk slot c of LDS
// row r holds GLOBAL chunk (c ^ (r&7)) -> XOR swizzle (2-way bank alias on
// ds_read_b128, free per m136), compatible with global_load_lds's strictly
// lane-ordered LDS destination (swizzle applied on the GLOBAL address).
//
// NEW this round:
//  * B-row permutation: LDS B-row (j*16 + lm) holds prototype (4*lm + j)
//    within each 64-col wave slab -> lane lm owns 4 CONTIGUOUS output
//    columns -> float4 (dwordx4) epilogue stores, float4 p2 load.
//  * Non-temporal output stores: 256 MiB store stream no longer evicts the
//    L2-resident xbf/pbf panels between K-steps.
//  * XCD-chunked tile remap (4096 blocks, %8==0 -> bijective): XCD x owns
//    M-rows [8x,8x+8), m-fastest inner order -> per-XCD working set
//    ~8 A-panels + ~16 B-panels ~ 1.5 MiB << 4 MiB L2.
//  * __launch_bounds__(256,4) + 32-bit staging offsets targeting 4 blk/CU.
// ---------------------------------------------------------------------------
__global__ void __launch_bounds__(256, 4) gauss_kernel(
    const unsigned short* __restrict__ xbf, const unsigned short* __restrict__ pbf,
    const float* __restrict__ x2, const float* __restrict__ p2,
    float* __restrict__ out) {
  __shared__ __align__(16) unsigned short lds_a[BM * BK];  // 16 KiB
  __shared__ __align__(16) unsigned short lds_b[BN * BK];  // 16 KiB

  const int t    = threadIdx.x;
  const int lane = t & 63;
  const int w    = t >> 6;        // wave 0..3
  const int wr   = w >> 1;        // wave row (0..1) -> 64-row slab of M
  const int wc   = w & 1;         // wave col (0..1) -> 64-col slab of N
  const int lm   = lane & 15;     // MFMA row/col-in-16
  const int q    = lane >> 4;     // quad 0..3
  const int sx   = lane & 7;      // swizzle xor (== row&7 for this lane's rows)

  // XCD-chunked tile remap. Linear dispatch id f is assigned round-robin to
  // XCD (f&7); give XCD x the contiguous M-row band [8x, 8x+8), sweeping
  // m fastest so concurrent tiles share B-panels within the band.
  const int f   = blockIdx.y * 64 + blockIdx.x;   // 0..4095
  const int xcd = f & 7;
  const int i2  = f >> 3;                         // 0..511
  const int M0  = (xcd * 8 + (i2 & 7)) * BM;
  const int N0  = (i2 >> 3) * BN;

  // Staging addresses: 1024 16B chunks per operand per K-step.
  // Chunk id L = I*256 + w*64 + lane; LDS placement is exactly lane order.
  unsigned int aOff[4], bOff[4];
  int ldsOff[4];
  #pragma unroll
  for (int I = 0; I < 4; ++I) {
    const int L = I * 256 + w * 64 + lane;
    const int r = L >> 3;                 // LDS row 0..127
    const int c = L & 7;                  // LDS chunk slot
    const int g = c ^ (r & 7);            // global chunk to fetch for slot c
    aOff[I] = (unsigned int)((M0 + r) * FDIM + g * 8);
    // B-row permutation: LDS row r holds prototype (r&64) + 4*(r&15) + ((r>>4)&3)
    const int pr = (r & 64) + 4 * (r & 15) + ((r >> 4) & 3);
    bOff[I] = (unsigned int)((N0 + pr) * FDIM + g * 8);
    ldsOff[I] = (I * 256 + w * 64) * 8;   // wave-uniform base (ushort elems)
  }

  floatx4 acc[4][4] = {};

  for (int s = 0; s < NSTEP; ++s) {
    __syncthreads();  // previous iteration's ds_reads complete before overwrite
    #pragma unroll
    for (int I = 0; I < 4; ++I) async16(xbf + aOff[I] + s * BK, &lds_a[ldsOff[I]]);
    #pragma unroll
    for (int I = 0; I < 4; ++I) async16(pbf + bOff[I] + s * BK, &lds_b[ldsOff[I]]);
    __syncthreads();  // drains vmcnt -> staged data visible

    #pragma unroll
    for (int kk = 0; kk < 2; ++kk) {   // two K=32 MFMA windows per BK=64
      const int slot = ((kk * 4 + q) ^ sx) * 8;      // swizzled 16B chunk
      const int aoff = (wr * 64 + lm) * BK + slot;
      const int boff = (wc * 64 + lm) * BK + slot;
      bf16x8 af[4], bfr[4];
      #pragma unroll
      for (int i = 0; i < 4; ++i) af[i]  = *(const bf16x8*)&lds_a[aoff + i * 16 * BK];
      #pragma unroll
      for (int j = 0; j < 4; ++j) bfr[j] = *(const bf16x8*)&lds_b[boff + j * 16 * BK];
      #pragma unroll
      for (int i = 0; i < 4; ++i)
        #pragma unroll
        for (int j = 0; j < 4; ++j)
          acc[i][j] = __builtin_amdgcn_mfma_f32_16x16x32_bf16(af[i], bfr[j], acc[i][j], 0, 0, 0);
    }
  }

  // Epilogue. C/D layout (16x16x32): fragment col = lane&15, row = q*4 + reg.
  // With the B permutation, accumulator j at lane lm is global column
  // N0 + wc*64 + 4*lm + j  -> contiguous float4 per lane.
  const floatx4 p2r = *reinterpret_cast<const floatx4*>(&p2[N0 + wc * 64 + 4 * lm]);
  const int ncol = N0 + wc * 64 + 4 * lm;

  #pragma unroll
  for (int i = 0; i < 4; ++i) {
    const int mbase = M0 + wr * 64 + i * 16 + q * 4;
    const floatx4 x2v = *reinterpret_cast<const floatx4*>(&x2[mbase]);
    #pragma unroll
    for (int v = 0; v < 4; ++v) {
      floatx4 res;
      #pragma unroll
      for (int j = 0; j < 4; ++j) {
        float d2 = x2v[v] + p2r[j] - 2.0f * acc[i][j][v];
        d2 = fmaxf(d2, 0.0f);
        const float dist = sqrtf(d2);
        res[j] = __expf(-0.5f * dist);   // denom = 2*sigma^2 = 2
      }
      floatx4* orow = (floatx4*)(out + (size_t)(mbase + v) * P_ROWS + ncol);
      __builtin_nontemporal_store(res, orow);  // don't evict xbf/pbf from L2
    }
  }
}

// ---------------------------------------------------------------------------
extern "C" void kernel_launch(void* const* d_in, const int* in_sizes, int n_in,
                              void* d_out, int out_size, void* d_ws, size_t ws_size,
                              hipStream_t stream) {
  const float* x = (const float*)d_in[0];
  const float* p = (const float*)d_in[1];
  float* out = (float*)d_out;

  // ws layout: xbf (4 MiB) | pbf (4 MiB) | x2 (32 KiB) | p2 (32 KiB)
  char* ws = (char*)d_ws;
  unsigned short* xbf = (unsigned short*)ws;
  unsigned short* pbf = (unsigned short*)(ws + (size_t)B_ROWS * FDIM * 2);
  float* x2 = (float*)(ws + (size_t)(B_ROWS + P_ROWS) * FDIM * 2);
  float* p2 = x2 + B_ROWS;

  prep_kernel<<<dim3(B_ROWS + P_ROWS), dim3(64), 0, stream>>>(x, p, xbf, pbf, x2, p2);

  dim3 grid(P_ROWS / BN, B_ROWS / BM);  // 64 x 64 = 4096 blocks
  gauss_kernel<<<grid, dim3(256), 0, stream>>>(xbf, pbf, x2, p2, out);
}